// Round 10
// baseline (89.245 us; speedup 1.0000x reference)
//
#include <hip/hip_runtime.h>
#include <math.h>

#define BB   32
#define CIN  16
#define HH   64
#define SS   128

// ---------------------------------------------------------------------------
// fused_front v5: weight-stationary f64 VALU GEMM.
// 512 thr = 8 waves. lane = output channel n (64); wave = K-slice (8).
// Each wave: weights (f32) for its K-slice in REGISTERS (read from global,
// original [n][K] layout is per-lane contiguous); acc = 16 positions in f64
// regs; data = wave-uniform double2 LDS broadcasts (0.5 LDS instr / FMA).
// Per phase: 2-round LDS tree reduction over the 8 K-slices, epilogue by
// waves 0-3 (each owns 4 positions). All accumulation f64 -> exact.
// ---------------------------------------------------------------------------

template <int KS>
__device__ __forceinline__ void fma_slice(const double* __restrict__ dat,
                                          const float* __restrict__ wrow,
                                          double* acc) {
    float wreg[KS];
    #pragma unroll
    for (int q = 0; q < KS; q += 2)
        *(float2*)(wreg + q) = *(const float2*)(wrow + q);
    #pragma unroll
    for (int p = 0; p < 16; ++p) acc[p] = 0.0;
    #pragma unroll 4
    for (int kk = 0; kk < KS; ++kk) {
        const double2* dr = (const double2*)(dat + kk * 16);
        double w = (double)wreg[kk];
        #pragma unroll
        for (int h2 = 0; h2 < 8; ++h2) {
            double2 dv = dr[h2];
            acc[2 * h2]     += dv.x * w;
            acc[2 * h2 + 1] += dv.y * w;
        }
    }
}

// 8-slice reduce. red layout: [slot(4)][p(16)][lane(64)] doubles (4096 total).
// On exit, waves 0-3 hold totals for p = 4*wave+q in tot[q].
__device__ __forceinline__ void reduce8(double* __restrict__ red,
                                        const double* __restrict__ acc,
                                        int wave, int lane, double* tot) {
    __syncthreads();                                     // A: FMAs done
    if (wave >= 4) {
        double* rp = red + (wave - 4) * 1024 + lane;
        #pragma unroll
        for (int p = 0; p < 16; ++p) rp[p * 64] = acc[p];
    }
    __syncthreads();                                     // B
    double acc2[16];
    if (wave < 4) {
        const double* rp = red + wave * 1024 + lane;
        #pragma unroll
        for (int p = 0; p < 16; ++p) acc2[p] = acc[p] + rp[p * 64];
    }
    __syncthreads();                                     // C: round-1 reads done
    if (wave < 4) {
        double* rp = red + wave * 1024 + lane;
        #pragma unroll
        for (int p = 0; p < 16; ++p) rp[p * 64] = acc2[p];
    }
    __syncthreads();                                     // D
    if (wave < 4) {
        #pragma unroll
        for (int q = 0; q < 4; ++q) {
            int p = 4 * wave + q;
            tot[q] = red[p * 64 + lane]        + red[1024 + p * 64 + lane]
                   + red[2048 + p * 64 + lane] + red[3072 + p * 64 + lane];
        }
    }
}

__global__ __launch_bounds__(512, 2) void fused_front(
    const float* __restrict__ x,
    const float* __restrict__ w11, const float* __restrict__ b11,
    const float* __restrict__ w12, const float* __restrict__ b12,
    const float* __restrict__ w21, const float* __restrict__ b21,
    const float* __restrict__ w22, const float* __restrict__ b22,
    const float* __restrict__ w31, const float* __restrict__ b31,
    const float* __restrict__ wf,  const float* __restrict__ bf,
    const float* __restrict__ w1,  const float* __restrict__ b1,
    double* __restrict__ Qg, double* __restrict__ Pg)
{
    const int b  = blockIdx.y;
    const int s0 = blockIdx.x * 16;
    const int t  = threadIdx.x;
    const int lane = t & 63, wave = t >> 6;

    // double region with overlays (doubles):
    //   [0,5120)      t2d  [320][16]
    //   [5120,6400)   x3d  [80][16]
    //   [6400,9472)   xf   [192][16]   (x123 in [k][p])
    //   [9472,10496)  h    [64][16]
    //   [10496,13568) t1d  [192][16]   (dead after conv12 FMAs)
    //   [10496,14592) red  [4][16][64] (overlays t1d + 1024 extra)
    __shared__ double S[14592];
    __shared__ float  xl[CIN][37];      // input window s0-10 .. s0+25
    __shared__ float  wA[2048];         // w11T/w21T [c][64]
    double* t2d = S;
    double* x3d = S + 5120;
    double* xf  = S + 6400;
    double* h   = S + 9472;
    double* t1d = S + 10496;
    double* red = S + 10496;

    // ---- stage 0: input window + transposed pointwise weights --------------
    for (int e = t; e < 2048; e += 512) {
        if (e < 1024) { int k = e >> 4, c = e & 15; wA[c * 64 + k] = w11[e]; }
        else { int j = e - 1024; int k = j >> 4, c = j & 15; wA[1024 + c * 64 + k] = w21[j]; }
    }
    for (int e = t; e < CIN * 36; e += 512) {
        int c = e / 36, col = e - c * 36;
        int g = s0 - 10 + col;
        xl[c][col] = (g >= 0 && g < SS) ? x[(b * CIN + c) * SS + g] : 0.f;
    }
    __syncthreads();

    // ---- stage A: pointwise convs -> [k][p] data arrays ---------------------
    for (int e = t; e < 1408; e += 512) {              // t1: 64ch x 22col
        int k = e & 63, col = e >> 6;
        int g = s0 - 3 + col;
        double val = 0.0;
        if (g >= 0 && g < SS) {
            double u0 = (double)b11[k], u1 = 0.0;
            #pragma unroll
            for (int c = 0; c < CIN; c += 2) {
                u0 += (double)xl[c][col + 7]     * (double)wA[c * 64 + k];
                u1 += (double)xl[c + 1][col + 7] * (double)wA[(c + 1) * 64 + k];
            }
            val = u0 + u1;
        }
        #pragma unroll
        for (int tp = 0; tp < 3; ++tp) {
            int p = col - 3 * tp;
            if (p >= 0 && p < 16) t1d[(k * 3 + tp) * 16 + p] = val;
        }
    }
    for (int e = t; e < 2304; e += 512) {              // t2: 64ch x 36col
        int k = e & 63, col = e >> 6;
        int g = s0 - 10 + col;
        double val = 0.0;
        if (g >= 0 && g < SS) {
            double u0 = (double)b21[k], u1 = 0.0;
            #pragma unroll
            for (int c = 0; c < CIN; c += 2) {
                u0 += (double)xl[c][col]     * (double)wA[1024 + c * 64 + k];
                u1 += (double)xl[c + 1][col] * (double)wA[1024 + (c + 1) * 64 + k];
            }
            val = u0 + u1;
        }
        #pragma unroll
        for (int tp = 0; tp < 5; ++tp) {
            int p = col - 5 * tp;
            if (p >= 0 && p < 16) t2d[(k * 5 + tp) * 16 + p] = val;
        }
    }
    for (int e = t; e < 1280; e += 512) {              // x3: [c*5+tp][p]
        int k = e >> 4, p = e & 15;
        int c = k / 5, tp = k - c * 5;
        x3d[e] = (double)xl[c][p + 8 + tp];
    }
    __syncthreads();

    double acc[16], tot[4];

    // ---- conv12: K=192, Ks=24 -> xf rows 0-63 ------------------------------
    fma_slice<24>(t1d + wave * 24 * 16, w12 + lane * 192 + wave * 24, acc);
    reduce8(red, acc, wave, lane, tot);
    if (wave < 4) {
        double bv = (double)b12[lane];
        #pragma unroll
        for (int q = 0; q < 4; ++q) xf[lane * 16 + 4 * wave + q] = tot[q] + bv;
    }
    __syncthreads();
    // ---- conv22: K=320, Ks=40 -> xf rows 64-127 ----------------------------
    fma_slice<40>(t2d + wave * 40 * 16, w22 + lane * 320 + wave * 40, acc);
    reduce8(red, acc, wave, lane, tot);
    if (wave < 4) {
        double bv = (double)b22[lane];
        #pragma unroll
        for (int q = 0; q < 4; ++q) xf[(64 + lane) * 16 + 4 * wave + q] = tot[q] + bv;
    }
    __syncthreads();
    // ---- conv31: K=80, Ks=10 -> xf rows 128-191 ----------------------------
    fma_slice<10>(x3d + wave * 10 * 16, w31 + lane * 80 + wave * 10, acc);
    reduce8(red, acc, wave, lane, tot);
    if (wave < 4) {
        double bv = (double)b31[lane];
        #pragma unroll
        for (int q = 0; q < 4; ++q) xf[(128 + lane) * 16 + 4 * wave + q] = tot[q] + bv;
    }
    __syncthreads();
    // ---- fc_final + relu: K=192, Ks=24 -> h --------------------------------
    fma_slice<24>(xf + wave * 24 * 16, wf + lane * 192 + wave * 24, acc);
    reduce8(red, acc, wave, lane, tot);
    if (wave < 4) {
        double bv = (double)bf[lane];
        #pragma unroll
        for (int q = 0; q < 4; ++q) {
            double v = tot[q] + bv;
            h[lane * 16 + 4 * wave + q] = v > 0.0 ? v : 0.0;
        }
    }
    __syncthreads();
    // ---- Q: K=64, Ks=8 -> Qg ------------------------------------------------
    fma_slice<8>(h + wave * 8 * 16, w1 + lane * 128 + wave * 8, acc);
    reduce8(red, acc, wave, lane, tot);
    if (wave < 4) {
        #pragma unroll
        for (int q = 0; q < 4; ++q) {
            int p = 4 * wave + q;
            Qg[((long)b * SS + s0 + p) * HH + lane] = tot[q];
        }
    }
    __syncthreads();
    // ---- P: K=64, Ks=8 -> Pg ------------------------------------------------
    fma_slice<8>(h + wave * 8 * 16, w1 + lane * 128 + 64 + wave * 8, acc);
    reduce8(red, acc, wave, lane, tot);
    if (wave < 4) {
        double bv = (double)b1[lane];
        #pragma unroll
        for (int q = 0; q < 4; ++q) {
            int p = 4 * wave + q;
            Pg[((long)b * SS + s0 + p) * HH + lane] = tot[q] + bv;
        }
    }
}

// ---------------------------------------------------------------------------
// Kernel 2: edge sign test (R9-identical, known-good). f32 fast path + exact
// f64 recompute for |acc| < 3e-3 (f32 error bound ~5e-5; deterministic).
// ---------------------------------------------------------------------------
__global__ __launch_bounds__(256) void edges(
    const double* __restrict__ Qg, const double* __restrict__ Pg,
    const float* __restrict__ w2, const float* __restrict__ b2,
    const float* __restrict__ gum, float* __restrict__ out)
{
    const int b   = blockIdx.y;
    const int tit = blockIdx.x >> 3;
    const int tjt = blockIdx.x & 7;
    const int t   = threadIdx.x;
    const int ti  = t >> 4, tj = t & 15;
    const int i   = tit * 16 + ti;
    const int j   = tjt * 16 + tj;
    float* op = out + ((long)b * SS + i) * SS + j;

    if (tjt < tit) { *op = 0.0f; return; }

    __shared__ float Plf[16][68];
    __shared__ float Qlf[16][68];
    __shared__ float dwl[64];

    if (t < 64) dwl[t] = w2[t] - w2[64 + t];
    for (int idx = t; idx < 1024; idx += 256) {
        int r = idx >> 6, c = idx & 63;
        Plf[r][c] = (float)Pg[((long)b * SS + tit * 16 + r) * HH + c];
        Qlf[r][c] = (float)Qg[((long)b * SS + tjt * 16 + r) * HH + c];
    }
    __syncthreads();

    if (j <= i) { *op = 0.0f; return; }

    long e = (long)b * SS * SS + (long)i * SS + j;
    const float2 uv = *(const float2*)(gum + e * 2);
    float basef = (b2[0] - b2[1]) - logf(-logf(uv.x)) + logf(-logf(uv.y));

    const float2* Pr = (const float2*)(&Plf[ti][0]);
    const float2* Qr = (const float2*)(&Qlf[tj][0]);
    const float2* Dr = (const float2*)dwl;
    float s0 = 0.f, s1 = 0.f;
    #pragma unroll
    for (int k2 = 0; k2 < 32; ++k2) {
        float2 pv = Pr[k2], qv = Qr[k2], dv = Dr[k2];
        float v0 = pv.x + qv.x; v0 = v0 > 0.f ? v0 : 0.f;
        float v1 = pv.y + qv.y; v1 = v1 > 0.f ? v1 : 0.f;
        s0 += v0 * dv.x; s1 += v1 * dv.y;
    }
    float tot = basef + s0 + s1;

    if (fabsf(tot) < 3e-3f) {
        const double* Prd = Pg + ((long)b * SS + i) * HH;
        const double* Qrd = Qg + ((long)b * SS + j) * HH;
        double acc = (double)b2[0] - (double)b2[1]
                   - log(-log((double)uv.x)) + log(-log((double)uv.y));
        for (int k = 0; k < 64; ++k) {
            double v = Prd[k] + Qrd[k];
            if (v > 0.0) acc += v * ((double)w2[k] - (double)w2[64 + k]);
        }
        *op = (acc >= 0.0) ? 1.0f : 0.0f;
    } else {
        *op = (tot >= 0.f) ? 1.0f : 0.0f;
    }
}

extern "C" void kernel_launch(void* const* d_in, const int* in_sizes, int n_in,
                              void* d_out, int out_size, void* d_ws, size_t ws_size,
                              hipStream_t stream) {
    const float* data = (const float*)d_in[0];
    const float* w11  = (const float*)d_in[1];
    const float* b11  = (const float*)d_in[2];
    const float* w12  = (const float*)d_in[3];
    const float* b12  = (const float*)d_in[4];
    const float* w21  = (const float*)d_in[5];
    const float* b21  = (const float*)d_in[6];
    const float* w22  = (const float*)d_in[7];
    const float* b22  = (const float*)d_in[8];
    const float* w31  = (const float*)d_in[9];
    const float* b31  = (const float*)d_in[10];
    const float* wf   = (const float*)d_in[11];
    const float* bf   = (const float*)d_in[12];
    const float* w1   = (const float*)d_in[13];
    const float* b1   = (const float*)d_in[14];
    const float* w2   = (const float*)d_in[15];
    const float* b2   = (const float*)d_in[16];
    const float* gum  = (const float*)d_in[17];
    float* out = (float*)d_out;

    double* Qg = (double*)d_ws;                      // 2 MB
    double* Pg = Qg + (long)BB * SS * HH;            // 2 MB

    fused_front<<<dim3(8, BB), 512, 0, stream>>>(
        data, w11, b11, w12, b12, w21, b21, w22, b22, w31, b31,
        wf, bf, w1, b1, Qg, Pg);
    edges<<<dim3(64, BB), 256, 0, stream>>>(Qg, Pg, w2, b2, gum, out);
}